// Round 2
// baseline (8689.718 us; speedup 1.0000x reference)
//
#include <hip/hip_runtime.h>
#include <math.h>

#define S_LEN 8192
#define L_CH 12

typedef _Float16 h2 __attribute__((ext_vector_type(2)));
typedef unsigned u32x2 __attribute__((ext_vector_type(2)));

static __device__ __forceinline__ h2 f2h2(float a, float b){
    h2 r; r.x = (_Float16)a; r.y = (_Float16)b; return r;
}

#if defined(__has_builtin)
#if __has_builtin(__builtin_amdgcn_fdot2)
#define HAVE_FDOT2 1
#endif
#if __has_builtin(__builtin_amdgcn_sdot4)
#define HAVE_SDOT4 1
#endif
#if __has_builtin(__builtin_amdgcn_permlane32_swap)
#define HAVE_PLSWAP 1
#endif
#endif

static __device__ __forceinline__ float fdot2(h2 a, h2 b, float c){
#ifdef HAVE_FDOT2
    return __builtin_amdgcn_fdot2(a, b, c, false);
#else
    asm("v_dot2_f32_f16 %0, %1, %2, %0" : "+v"(c) : "v"(a), "v"(b));
    return c;
#endif
}

static __device__ __forceinline__ int sdot4(int a, int b, int c){
#ifdef HAVE_SDOT4
    return __builtin_amdgcn_sdot4(a, b, c, false);
#else
    asm("v_dot4_i32_i8 %0, %1, %2, %0" : "+v"(c) : "v"(a), "v"(b));
    return c;
#endif
}

// cross-half (lane xor 32) sum of two accumulators, results replicated to all
// lanes: x_all = a.lo+a.hi (everywhere), y_all = b.lo+b.hi (everywhere).
static __device__ __forceinline__ void reduce_pair(int a, int b, int& x_all, int& y_all){
#ifdef HAVE_PLSWAP
    u32x2 r1 = __builtin_amdgcn_permlane32_swap((unsigned)a, (unsigned)b, false, false);
    int s = (int)r1.x + (int)r1.y;            // lanes<32: a_tot, lanes>=32: b_tot
    u32x2 r2 = __builtin_amdgcn_permlane32_swap((unsigned)s, (unsigned)s, false, false);
    x_all = (int)r2.x;                        // lo half replicated = a_tot
    y_all = (int)r2.y;                        // hi half replicated = b_tot
#else
    int s1 = a, s2 = b;
    asm volatile("v_permlane32_swap_b32 %0, %1" : "+v"(s1), "+v"(s2));
    int s = s1 + s2;
    int u = s, v = s;
    asm volatile("v_permlane32_swap_b32 %0, %1" : "+v"(u), "+v"(v));
    x_all = u; y_all = v;
#endif
}

static __device__ __forceinline__ float fast_sig(float x){
    return 1.0f / (1.0f + __expf(-x));
}
static __device__ __forceinline__ float fast_tanh(float x){
    float ax = fabsf(x);
    float e = __expf(2.0f * ax);
    float t = 1.0f - 2.0f / (e + 1.0f);
    return copysignf(t, x);
}

// ---------------- kernel 0: quantize w_whh (1024x256 f32) to i8 + per-row scale
__global__ __launch_bounds__(64) void k_quant(const float* __restrict__ whh,
                                              int* __restrict__ wq,
                                              float* __restrict__ fsc){
    int r = blockIdx.x;          // 1024 rows
    int k = threadIdx.x;         // 64 lanes, 4 elems each
    float4 v = ((const float4*)(whh + (size_t)r * 256))[k];
    float m = fmaxf(fmaxf(fabsf(v.x), fabsf(v.y)), fmaxf(fabsf(v.z), fabsf(v.w)));
    #pragma unroll
    for (int off = 32; off; off >>= 1) m = fmaxf(m, __shfl_xor(m, off));
    float inv = (m > 0.f) ? (127.0f / m) : 0.0f;
    int q0 = ((int)rintf(v.x * inv)) & 255;
    int q1 = ((int)rintf(v.y * inv)) & 255;
    int q2 = ((int)rintf(v.z * inv)) & 255;
    int q3 = ((int)rintf(v.w * inv)) & 255;
    wq[r * 64 + k] = q0 | (q1 << 8) | (q2 << 16) | (q3 << 24);
    if (k == 0) fsc[r] = m * (1.0f / (127.0f * 127.0f));  // sw * sh, sh = 1/127
}

// ---------------- kernel 1: char LSTM (+ assemble wx = [word_emb | h_char])
__global__ __launch_bounds__(256) void k_char(const int* __restrict__ word_ixs,
                                              const int* __restrict__ char_ixs,
                                              const int* __restrict__ char_lens,
                                              const float* __restrict__ word_emb,
                                              const float* __restrict__ char_emb,
                                              const float* __restrict__ c_wih,
                                              const float* __restrict__ c_whh,
                                              const float* __restrict__ c_bih,
                                              const float* __restrict__ c_bhh,
                                              float* __restrict__ wx){
    __shared__ h2 xh[32];      // x_t as f16 pairs (64 vals)
    __shared__ h2 hh[32];      // h as f16 pairs (64 vals)
    __shared__ float zbuf[256];
    int tid = threadIdx.x;
    // per-thread weight row (row = tid of the 256 gate rows), f16-packed in regs
    h2 wi[32], wh[32];
    {
        const float2* a = (const float2*)(c_wih + (size_t)tid * 64);
        const float2* b = (const float2*)(c_whh + (size_t)tid * 64);
        #pragma unroll
        for (int d = 0; d < 32; ++d){ float2 v = a[d]; wi[d] = f2h2(v.x, v.y); }
        #pragma unroll
        for (int d = 0; d < 32; ++d){ float2 v = b[d]; wh[d] = f2h2(v.x, v.y); }
    }
    float cb = c_bih[tid] + c_bhh[tid];

    for (int w = 0; w < 4; ++w){
        int s = blockIdx.x * 4 + w;
        int len = char_lens[s];
        __syncthreads();                       // prev word's hh writes done
        if (tid < 32) hh[tid] = (h2)0.0f;
        float c_state = 0.f, h_state = 0.f;
        for (int t = 0; t < len; ++t){
            if (tid < 32){
                int ci = char_ixs[s * L_CH + t];
                float2 v = ((const float2*)(char_emb + (size_t)ci * 64))[tid];
                xh[tid] = f2h2(v.x, v.y);
            }
            __syncthreads();                   // x staged, h from prev step visible
            float acc = cb;
            #pragma unroll
            for (int d = 0; d < 32; ++d) acc = fdot2(wi[d], xh[d], acc);
            #pragma unroll
            for (int d = 0; d < 32; ++d) acc = fdot2(wh[d], hh[d], acc);
            zbuf[tid] = acc;
            __syncthreads();                   // z exchanged; hh reads done
            if (tid < 64){
                float zi = zbuf[tid], zf = zbuf[64 + tid];
                float zg = zbuf[128 + tid], zo = zbuf[192 + tid];
                c_state = fast_sig(zf) * c_state + fast_sig(zi) * fast_tanh(zg);
                h_state = fast_sig(zo) * fast_tanh(c_state);
                ((_Float16*)hh)[tid] = (_Float16)h_state;
            }
        }
        int wix = word_ixs[s];
        if (tid < 128) wx[(size_t)s * 192 + tid] = word_emb[(size_t)wix * 128 + tid];
        if (tid < 64)  wx[(size_t)s * 192 + 128 + tid] = h_state;
    }
}

// ---------------- kernel 2: zx = wx @ w_wih.T + (w_bih + w_bhh)
__global__ __launch_bounds__(128) void k_proj(const float* __restrict__ wx,
                                              const float* __restrict__ w_wih,
                                              const float* __restrict__ w_bih,
                                              const float* __restrict__ w_bhh,
                                              float* __restrict__ zx){
    __shared__ h2 xl[96];
    int tid = threadIdx.x;
    int jt = blockIdx.x & 7;        // 8 j-tiles of 128
    int sc = blockIdx.x >> 3;       // 128 s-chunks of 64
    int j  = jt * 128 + tid;
    h2 wreg[96];
    {
        const float2* wr = (const float2*)(w_wih + (size_t)j * 192);
        #pragma unroll
        for (int d = 0; d < 96; ++d){ float2 v = wr[d]; wreg[d] = f2h2(v.x, v.y); }
    }
    float wb = w_bih[j] + w_bhh[j];
    for (int i = 0; i < 64; ++i){
        int s = sc * 64 + i;
        __syncthreads();
        if (tid < 96){
            float2 v = ((const float2*)(wx + (size_t)s * 192))[tid];
            xl[tid] = f2h2(v.x, v.y);
        }
        __syncthreads();
        float acc = wb;
        #pragma unroll
        for (int d = 0; d < 96; ++d) acc = fdot2(wreg[d], xl[d], acc);
        zx[(size_t)s * 1024 + j] = acc;
    }
}

// ---------------- kernel 3: sequential word-LSTM scan (single workgroup)
// 512 threads = 8 waves. Wave w owns elements 32w..32w+31.
// Lane l: element e = 32w + (l&31); K-half = l>>5 (dims half*128..half*128+127).
// Per lane: 4 gate rows (i=e, f=e+256, g=e+512, o=e+768) x 32 weight ints in VGPRs.
// Cross-half reduce via v_permlane32_swap (VALU), gates fully lane-local,
// ONE barrier per step.
__global__ __attribute__((amdgpu_flat_work_group_size(512,512)))
__attribute__((amdgpu_waves_per_eu(2,2)))
void k_scan(const float* __restrict__ zx,
            const int* __restrict__ wq,
            const float* __restrict__ fsc,
            float* __restrict__ hs){
    __shared__ alignas(16) int hq[2][64];   // h quantized i8, double-buffered
    int tid  = threadIdx.x;
    int lane = tid & 63;
    int wv   = tid >> 6;                 // wave 0..7
    int e    = (wv << 5) + (lane & 31);  // element 0..255
    int half = lane >> 5;                // K-half 0/1

    // weights: rows e, e+256, e+512, e+768; ints [half*32 .. half*32+31]
    int4 wr0[8], wr1[8], wr2[8], wr3[8];
    {
        const int4* p0 = (const int4*)(wq + (size_t)(e        ) * 64 + half * 32);
        const int4* p1 = (const int4*)(wq + (size_t)(e +  256 ) * 64 + half * 32);
        const int4* p2 = (const int4*)(wq + (size_t)(e +  512 ) * 64 + half * 32);
        const int4* p3 = (const int4*)(wq + (size_t)(e +  768 ) * 64 + half * 32);
        #pragma unroll
        for (int j = 0; j < 8; ++j){ wr0[j] = p0[j]; wr1[j] = p1[j]; wr2[j] = p2[j]; wr3[j] = p3[j]; }
    }
    float fs0 = fsc[e], fs1 = fsc[e + 256], fs2 = fsc[e + 512], fs3 = fsc[e + 768];

    if (tid < 64) hq[0][tid] = 0;
    float c_state = 0.f;

    // zx prefetch, 2 steps ahead; 4 rows per lane (i,f,g,o)
    const float* zc = zx + e;
    float za0 = zc[0], za1 = zc[256], za2 = zc[512], za3 = zc[768];
    zc += 1024;
    float zb0 = zc[0], zb1 = zc[256], zb2 = zc[512], zb3 = zc[768];

    float* hsp = hs + e;
    __syncthreads();

    #pragma unroll 2
    for (int t = 0; t < S_LEN; ++t){
        float z0 = za0, z1 = za1, z2 = za2, z3 = za3;
        za0 = zb0; za1 = zb1; za2 = zb2; za3 = zb3;
        if (t < S_LEN - 2) zc += 1024;          // clamp: avoid OOB prefetch
        zb0 = zc[0]; zb1 = zc[256]; zb2 = zc[512]; zb3 = zc[768];

        // read my K-half of h: 8 x ds_read_b128 (2 unique 16B lines, broadcast)
        const int4* hp = ((const int4*)hq[t & 1]) + (half << 3);
        int4 h0 = hp[0], h1 = hp[1], h2v = hp[2], h3 = hp[3];
        int4 h4 = hp[4], h5 = hp[5], h6  = hp[6], h7 = hp[7];

        int ai = 0, af = 0, ag = 0, ao = 0;
        #pragma unroll
        for (int j = 0; j < 8; ++j){
            int4 hv = (j==0)?h0:(j==1)?h1:(j==2)?h2v:(j==3)?h3:(j==4)?h4:(j==5)?h5:(j==6)?h6:h7;
            ai = sdot4(wr0[j].x, hv.x, ai); ai = sdot4(wr0[j].y, hv.y, ai);
            ai = sdot4(wr0[j].z, hv.z, ai); ai = sdot4(wr0[j].w, hv.w, ai);
            af = sdot4(wr1[j].x, hv.x, af); af = sdot4(wr1[j].y, hv.y, af);
            af = sdot4(wr1[j].z, hv.z, af); af = sdot4(wr1[j].w, hv.w, af);
            ag = sdot4(wr2[j].x, hv.x, ag); ag = sdot4(wr2[j].y, hv.y, ag);
            ag = sdot4(wr2[j].z, hv.z, ag); ag = sdot4(wr2[j].w, hv.w, ag);
            ao = sdot4(wr3[j].x, hv.x, ao); ao = sdot4(wr3[j].y, hv.y, ao);
            ao = sdot4(wr3[j].z, hv.z, ao); ao = sdot4(wr3[j].w, hv.w, ao);
        }

        int i_all, f_all, g_all, o_all;
        reduce_pair(ai, af, i_all, f_all);
        reduce_pair(ag, ao, g_all, o_all);

        float zi = fmaf((float)i_all, fs0, z0);
        float zf = fmaf((float)f_all, fs1, z1);
        float zg = fmaf((float)g_all, fs2, z2);
        float zo = fmaf((float)o_all, fs3, z3);

        float p = fast_sig(zi) * fast_tanh(zg);
        c_state = fast_sig(zf) * c_state + p;
        float h = fast_sig(zo) * fast_tanh(c_state);

        if (half == 0){
            hsp[0] = h;
            int q = (int)rintf(h * 127.0f);
            ((signed char*)hq[(t + 1) & 1])[e] = (signed char)q;
        }
        hsp += 256;
        __syncthreads();
    }
}

// ---------------- kernel 4: logits + log_softmax
__global__ __launch_bounds__(128) void k_out(const float* __restrict__ hs,
                                             const float* __restrict__ out_w,
                                             const float* __restrict__ out_b,
                                             float* __restrict__ out){
    __shared__ float hl[256];
    __shared__ float red0[2];
    __shared__ float red1[2];
    int s = blockIdx.x, tid = threadIdx.x;
    hl[tid]       = hs[(size_t)s * 256 + tid];
    hl[tid + 128] = hs[(size_t)s * 256 + 128 + tid];
    __syncthreads();
    const float4* wr = (const float4*)(out_w + (size_t)tid * 256);
    float acc = out_b[tid];
    #pragma unroll 8
    for (int k = 0; k < 64; ++k){
        float4 v = wr[k];
        acc += v.x * hl[4*k] + v.y * hl[4*k+1] + v.z * hl[4*k+2] + v.w * hl[4*k+3];
    }
    float m = acc;
    #pragma unroll
    for (int off = 32; off; off >>= 1) m = fmaxf(m, __shfl_xor(m, off));
    if ((tid & 63) == 0) red0[tid >> 6] = m;
    __syncthreads();
    float M = fmaxf(red0[0], red0[1]);
    float e = __expf(acc - M);
    float ssum = e;
    #pragma unroll
    for (int off = 32; off; off >>= 1) ssum += __shfl_xor(ssum, off);
    if ((tid & 63) == 0) red1[tid >> 6] = ssum;
    __syncthreads();
    float Z = red1[0] + red1[1];
    out[(size_t)s * 128 + tid] = acc - M - __logf(Z);
}

extern "C" void kernel_launch(void* const* d_in, const int* in_sizes, int n_in,
                              void* d_out, int out_size, void* d_ws, size_t ws_size,
                              hipStream_t stream){
    const int*   word_ixs  = (const int*)  d_in[0];
    const int*   char_ixs  = (const int*)  d_in[1];
    const int*   char_lens = (const int*)  d_in[2];
    const float* word_emb  = (const float*)d_in[3];
    const float* char_emb  = (const float*)d_in[4];
    const float* c_wih     = (const float*)d_in[5];
    const float* c_whh     = (const float*)d_in[6];
    const float* c_bih     = (const float*)d_in[7];
    const float* c_bhh     = (const float*)d_in[8];
    const float* w_wih     = (const float*)d_in[9];
    const float* w_whh     = (const float*)d_in[10];
    const float* w_bih     = (const float*)d_in[11];
    const float* w_bhh     = (const float*)d_in[12];
    const float* out_w     = (const float*)d_in[13];
    const float* out_b     = (const float*)d_in[14];
    float* out = (float*)d_out;

    char* ws = (char*)d_ws;
    // workspace layout (all 16B aligned)
    const size_t OFF_WX  = 0;                        // 8192*192*4  = 6291456
    const size_t OFF_ZX  = OFF_WX + 6291456;         // 8192*1024*4 = 33554432
    const size_t OFF_HS  = OFF_ZX + 33554432;        // 8192*256*4  = 8388608
    const size_t OFF_WQ  = OFF_HS + 8388608;         // 1024*256    = 262144
    const size_t OFF_FS  = OFF_WQ + 262144;          // 1024*4      = 4096
    float* wx  = (float*)(ws + OFF_WX);
    float* zx  = (float*)(ws + OFF_ZX);
    float* hs  = (float*)(ws + OFF_HS);
    int*   wq  = (int*)  (ws + OFF_WQ);
    float* fsc = (float*)(ws + OFF_FS);

    k_quant<<<dim3(1024), dim3(64),  0, stream>>>(w_whh, wq, fsc);
    k_char <<<dim3(2048), dim3(256), 0, stream>>>(word_ixs, char_ixs, char_lens,
                                                  word_emb, char_emb,
                                                  c_wih, c_whh, c_bih, c_bhh, wx);
    k_proj <<<dim3(1024), dim3(128), 0, stream>>>(wx, w_wih, w_bih, w_bhh, zx);
    k_scan <<<dim3(1),    dim3(512), 0, stream>>>(zx, wq, fsc, hs);
    k_out  <<<dim3(8192), dim3(128), 0, stream>>>(hs, out_w, out_b, out);
}

// Round 5
// 8169.772 us; speedup vs baseline: 1.0636x; 1.0636x over previous
//
#include <hip/hip_runtime.h>
#include <math.h>

#define S_LEN 8192
#define L_CH 12

typedef _Float16 h2 __attribute__((ext_vector_type(2)));
typedef unsigned u32x2 __attribute__((ext_vector_type(2)));

static __device__ __forceinline__ h2 f2h2(float a, float b){
    h2 r; r.x = (_Float16)a; r.y = (_Float16)b; return r;
}

#if defined(__has_builtin)
#if __has_builtin(__builtin_amdgcn_fdot2)
#define HAVE_FDOT2 1
#endif
#if __has_builtin(__builtin_amdgcn_sdot4)
#define HAVE_SDOT4 1
#endif
#if __has_builtin(__builtin_amdgcn_permlane32_swap)
#define HAVE_PLSWAP 1
#endif
#if __has_builtin(__builtin_amdgcn_permlane16_swap)
#define HAVE_PL16SWAP 1
#endif
#endif

static __device__ __forceinline__ float fdot2(h2 a, h2 b, float c){
#ifdef HAVE_FDOT2
    return __builtin_amdgcn_fdot2(a, b, c, false);
#else
    asm("v_dot2_f32_f16 %0, %1, %2, %0" : "+v"(c) : "v"(a), "v"(b));
    return c;
#endif
}

static __device__ __forceinline__ int sdot4(int a, int b, int c){
#ifdef HAVE_SDOT4
    return __builtin_amdgcn_sdot4(a, b, c, false);
#else
    asm("v_dot4_i32_i8 %0, %1, %2, %0" : "+v"(c) : "v"(a), "v"(b));
    return c;
#endif
}

// stage-1 reduce: xor-32 distributing sum. TRUE HW semantics (verified R2):
//   lanes<32  -> sum32(a) = a(l)+a(l^32)
//   lanes>=32 -> sum32(b) = b(l)+b(l^32)
static __device__ __forceinline__ int swap32_sum(int a, int b){
#ifdef HAVE_PLSWAP
    u32x2 r = __builtin_amdgcn_permlane32_swap((unsigned)a, (unsigned)b, false, false);
    return (int)r.x + (int)r.y;
#else
    asm volatile("v_permlane32_swap_b32 %0, %1" : "+v"(a), "+v"(b));
    return a + b;
#endif
}

// stage-2 reduce: xor-16 distributing sum. TRUE HW semantics:
//   (lane&16)==0 -> sum16(a) = a(l)+a(l^16)
//   (lane&16)!=0 -> sum16(b) = b(l)+b(l^16)
static __device__ __forceinline__ int swap16_sum(int a, int b){
#ifdef HAVE_PL16SWAP
    u32x2 r = __builtin_amdgcn_permlane16_swap((unsigned)a, (unsigned)b, false, false);
    return (int)r.x + (int)r.y;
#else
    int sa = a + __builtin_amdgcn_ds_swizzle(a, 0x401F);   // xor16 replicate-sum
    int sb = b + __builtin_amdgcn_ds_swizzle(b, 0x401F);
    return (threadIdx.x & 16) ? sb : sa;
#endif
}

// deliver p's xor-16 partner value to the UPPER row lanes (lane&16 != 0).
// permlane16_swap(p,p).x: rows 16-31 receive partner's p; rows 0-15 keep own.
static __device__ __forceinline__ float xchg16_to_hi(float p){
#ifdef HAVE_PL16SWAP
    u32x2 r = __builtin_amdgcn_permlane16_swap((unsigned)__float_as_int(p),
                                               (unsigned)__float_as_int(p), false, false);
    return __int_as_float((int)r.x);
#else
    return __int_as_float(__builtin_amdgcn_ds_swizzle(__float_as_int(p), 0x401F));
#endif
}

static __device__ __forceinline__ float fast_sig(float x){
    return 1.0f / (1.0f + __expf(-x));
}
static __device__ __forceinline__ float fast_tanh(float x){
    float ax = fabsf(x);
    float e = __expf(2.0f * ax);
    float t = 1.0f - 2.0f / (e + 1.0f);
    return copysignf(t, x);
}

// ---------------- kernel 0: quantize w_whh (1024x256 f32) to i8 + per-row scale
__global__ __launch_bounds__(64) void k_quant(const float* __restrict__ whh,
                                              int* __restrict__ wq,
                                              float* __restrict__ fsc){
    int r = blockIdx.x;          // 1024 rows
    int k = threadIdx.x;         // 64 lanes, 4 elems each
    float4 v = ((const float4*)(whh + (size_t)r * 256))[k];
    float m = fmaxf(fmaxf(fabsf(v.x), fabsf(v.y)), fmaxf(fabsf(v.z), fabsf(v.w)));
    #pragma unroll
    for (int off = 32; off; off >>= 1) m = fmaxf(m, __shfl_xor(m, off));
    float inv = (m > 0.f) ? (127.0f / m) : 0.0f;
    int q0 = ((int)rintf(v.x * inv)) & 255;
    int q1 = ((int)rintf(v.y * inv)) & 255;
    int q2 = ((int)rintf(v.z * inv)) & 255;
    int q3 = ((int)rintf(v.w * inv)) & 255;
    wq[r * 64 + k] = q0 | (q1 << 8) | (q2 << 16) | (q3 << 24);
    if (k == 0) fsc[r] = m * (1.0f / (127.0f * 127.0f));  // sw * sh, sh = 1/127
}

// ---------------- kernel 1: char LSTM (+ assemble wx = [word_emb | h_char])
__global__ __launch_bounds__(256) void k_char(const int* __restrict__ word_ixs,
                                              const int* __restrict__ char_ixs,
                                              const int* __restrict__ char_lens,
                                              const float* __restrict__ word_emb,
                                              const float* __restrict__ char_emb,
                                              const float* __restrict__ c_wih,
                                              const float* __restrict__ c_whh,
                                              const float* __restrict__ c_bih,
                                              const float* __restrict__ c_bhh,
                                              float* __restrict__ wx){
    __shared__ h2 xh[32];      // x_t as f16 pairs (64 vals)
    __shared__ h2 hh[32];      // h as f16 pairs (64 vals)
    __shared__ float zbuf[256];
    int tid = threadIdx.x;
    h2 wi[32], wh[32];
    {
        const float2* a = (const float2*)(c_wih + (size_t)tid * 64);
        const float2* b = (const float2*)(c_whh + (size_t)tid * 64);
        #pragma unroll
        for (int d = 0; d < 32; ++d){ float2 v = a[d]; wi[d] = f2h2(v.x, v.y); }
        #pragma unroll
        for (int d = 0; d < 32; ++d){ float2 v = b[d]; wh[d] = f2h2(v.x, v.y); }
    }
    float cb = c_bih[tid] + c_bhh[tid];

    for (int w = 0; w < 4; ++w){
        int s = blockIdx.x * 4 + w;
        int len = char_lens[s];
        __syncthreads();
        if (tid < 32) hh[tid] = (h2)0.0f;
        float c_state = 0.f, h_state = 0.f;
        for (int t = 0; t < len; ++t){
            if (tid < 32){
                int ci = char_ixs[s * L_CH + t];
                float2 v = ((const float2*)(char_emb + (size_t)ci * 64))[tid];
                xh[tid] = f2h2(v.x, v.y);
            }
            __syncthreads();
            float acc = cb;
            #pragma unroll
            for (int d = 0; d < 32; ++d) acc = fdot2(wi[d], xh[d], acc);
            #pragma unroll
            for (int d = 0; d < 32; ++d) acc = fdot2(wh[d], hh[d], acc);
            zbuf[tid] = acc;
            __syncthreads();
            if (tid < 64){
                float zi = zbuf[tid], zf = zbuf[64 + tid];
                float zg = zbuf[128 + tid], zo = zbuf[192 + tid];
                c_state = fast_sig(zf) * c_state + fast_sig(zi) * fast_tanh(zg);
                h_state = fast_sig(zo) * fast_tanh(c_state);
                ((_Float16*)hh)[tid] = (_Float16)h_state;
            }
        }
        int wix = word_ixs[s];
        if (tid < 128) wx[(size_t)s * 192 + tid] = word_emb[(size_t)wix * 128 + tid];
        if (tid < 64)  wx[(size_t)s * 192 + 128 + tid] = h_state;
    }
}

// ---------------- kernel 2: zx = wx @ w_wih.T + (w_bih + w_bhh)
__global__ __launch_bounds__(128) void k_proj(const float* __restrict__ wx,
                                              const float* __restrict__ w_wih,
                                              const float* __restrict__ w_bih,
                                              const float* __restrict__ w_bhh,
                                              float* __restrict__ zx){
    __shared__ h2 xl[96];
    int tid = threadIdx.x;
    int jt = blockIdx.x & 7;
    int sc = blockIdx.x >> 3;
    int j  = jt * 128 + tid;
    h2 wreg[96];
    {
        const float2* wr = (const float2*)(w_wih + (size_t)j * 192);
        #pragma unroll
        for (int d = 0; d < 96; ++d){ float2 v = wr[d]; wreg[d] = f2h2(v.x, v.y); }
    }
    float wb = w_bih[j] + w_bhh[j];
    for (int i = 0; i < 64; ++i){
        int s = sc * 64 + i;
        __syncthreads();
        if (tid < 96){
            float2 v = ((const float2*)(wx + (size_t)s * 192))[tid];
            xl[tid] = f2h2(v.x, v.y);
        }
        __syncthreads();
        float acc = wb;
        #pragma unroll
        for (int d = 0; d < 96; ++d) acc = fdot2(wreg[d], xl[d], acc);
        zx[(size_t)s * 1024 + j] = acc;
    }
}

// ---------------- kernel 3: sequential word-LSTM scan (single workgroup)
// 512 threads = 8 waves. Wave wv owns elements wv*32..wv*32+31.
// Lane bits: s16 = l&15, b4 = (l>>4)&1, b5 = l>>5; K-quarter q4 = l>>4 (64 dims).
// Dot phase: lane computes 8 partial accs = {e0, e1} x {i,f,g,o} over its K-quarter,
//   e0 = wv*32+s16, e1 = e0+16.  Weights FORCED into VGPRs via asm-opacity.
// Reduce (TRUE permlane semantics): stage-1 b5=0 -> e0, b5=1 -> e1;
//   stage-2 b4=0 -> first arg {i,g}, b4=1 -> second arg {f,o}.
// Gates: b4=0 lanes form p = sig(i)*tanh(g); xchg16_to_hi hands p to b4=1 lanes,
//   which carry c-state, produce h, write hq (i8, dbuf) + hs. ONE barrier/step.
__global__ __attribute__((amdgpu_flat_work_group_size(512,512)))
__attribute__((amdgpu_waves_per_eu(2,2)))
void k_scan(const float* __restrict__ zx,
            const int* __restrict__ wq,
            const float* __restrict__ fsc,
            float* __restrict__ hs){
    __shared__ alignas(16) int hq[2][64];
    int tid  = threadIdx.x;
    int lane = tid & 63;
    int wv   = tid >> 6;
    int s16  = lane & 15;
    int b4   = (lane >> 4) & 1;
    int b5   = lane >> 5;
    int q4   = lane >> 4;            // K-quarter 0..3
    int e0   = (wv << 5) + s16;
    int e1   = e0 + 16;
    int qoff = q4 << 4;              // int offset of my K-quarter within a row

    // my post-reduce element + gate-row pair (TRUE orientation):
    // b5=0 lanes own e0, b5=1 own e1; b4=0 -> (i,g) rows, b4=1 -> (f,o) rows.
    int e  = b5 ? e1 : e0;
    int ra = e + (b4 ? 256 : 0);     // f-row (b4=1) | i-row (b4=0)
    int rb = e + (b4 ? 768 : 512);   // o-row (b4=1) | g-row (b4=0)

#define WLOAD(n, row) \
    int4 w##n##_0, w##n##_1, w##n##_2, w##n##_3; \
    { const int4* p_ = (const int4*)(wq + (size_t)(row) * 64 + qoff); \
      w##n##_0 = p_[0]; w##n##_1 = p_[1]; w##n##_2 = p_[2]; w##n##_3 = p_[3]; }
#define OPQ(v) asm volatile("" : "+v"(v.x), "+v"(v.y), "+v"(v.z), "+v"(v.w))
#define OPQR(n) OPQ(w##n##_0); OPQ(w##n##_1); OPQ(w##n##_2); OPQ(w##n##_3)

    WLOAD(0, e0      ); WLOAD(1, e0 + 256); WLOAD(2, e0 + 512); WLOAD(3, e0 + 768);
    WLOAD(4, e1      ); WLOAD(5, e1 + 256); WLOAD(6, e1 + 512); WLOAD(7, e1 + 768);
    OPQR(0); OPQR(1); OPQR(2); OPQR(3); OPQR(4); OPQR(5); OPQR(6); OPQR(7);

    float fa = fsc[ra], fb = fsc[rb];

    if (tid < 64) hq[0][tid] = 0;
    float c_state = 0.f;

    // zx prefetch, 2 steps ahead (rows ra, rb only)
    const float* zc = zx;
    float zA = zc[ra], zB = zc[rb];
    zc += 1024;
    float zA1 = zc[ra], zB1 = zc[rb];

    float* hsp = hs + e;
    __syncthreads();

#define DOTR(acc, n) \
    acc = sdot4(w##n##_0.x, hv0.x, acc); acc = sdot4(w##n##_0.y, hv0.y, acc); \
    acc = sdot4(w##n##_0.z, hv0.z, acc); acc = sdot4(w##n##_0.w, hv0.w, acc); \
    acc = sdot4(w##n##_1.x, hv1.x, acc); acc = sdot4(w##n##_1.y, hv1.y, acc); \
    acc = sdot4(w##n##_1.z, hv1.z, acc); acc = sdot4(w##n##_1.w, hv1.w, acc); \
    acc = sdot4(w##n##_2.x, hv2.x, acc); acc = sdot4(w##n##_2.y, hv2.y, acc); \
    acc = sdot4(w##n##_2.z, hv2.z, acc); acc = sdot4(w##n##_2.w, hv2.w, acc); \
    acc = sdot4(w##n##_3.x, hv3.x, acc); acc = sdot4(w##n##_3.y, hv3.y, acc); \
    acc = sdot4(w##n##_3.z, hv3.z, acc); acc = sdot4(w##n##_3.w, hv3.w, acc)

    #pragma unroll 2
    for (int t = 0; t < S_LEN; ++t){
        float curA = zA, curB = zB;
        zA = zA1; zB = zB1;
        if (t < S_LEN - 2) zc += 1024;      // clamp: avoid OOB prefetch
        zA1 = zc[ra]; zB1 = zc[rb];

        // read my K-quarter of h: 4 x ds_read_b128 (same addr within 16-lane group)
        const int4* hp = (const int4*)((const int*)hq[t & 1] + qoff);
        int4 hv0 = hp[0], hv1 = hp[1], hv2 = hp[2], hv3 = hp[3];

        int a0 = 0, a1 = 0, a2 = 0, a3 = 0, a4 = 0, a5 = 0, a6 = 0, a7 = 0;
        DOTR(a0, 0); DOTR(a4, 4);
        DOTR(a1, 1); DOTR(a5, 5);
        DOTR(a2, 2); DOTR(a6, 6);
        DOTR(a3, 3); DOTR(a7, 7);

        // stage 1: b5=0 lanes -> e0 sums, b5=1 -> e1 sums (quarters {b4, b4+2})
        int si = swap32_sum(a0, a4);
        int sf = swap32_sum(a1, a5);
        int sg = swap32_sum(a2, a6);
        int so = swap32_sum(a3, a7);
        // stage 2: full-K sums, distributed: b4=0 -> (i,g), b4=1 -> (f,o)
        int red_a = swap16_sum(si, sf);
        int red_b = swap16_sum(sg, so);

        float va = fmaf((float)red_a, fa, curA);   // z_i (b4=0) | z_f (b4=1)
        float vb = fmaf((float)red_b, fb, curB);   // z_g (b4=0) | z_o (b4=1)

        float sa = fast_sig(va);                   // sig(i) | sig(f)
        float p  = sa * fast_tanh(vb);             // i*tanh(g)  (valid on b4=0)
        float sb = fast_sig(vb);                   // sig(o)     (valid on b4=1)
        float pr = xchg16_to_hi(p);                // b4=1 lanes get partner's p

        c_state = sa * c_state + pr;               // valid on b4=1 lanes
        float h = sb * fast_tanh(c_state);

        if (b4 == 1){
            hsp[0] = h;
            int q = (int)rintf(h * 127.0f);
            ((signed char*)hq[(t + 1) & 1])[e] = (signed char)q;
        }
        hsp += 256;
        __syncthreads();
    }
#undef DOTR
#undef WLOAD
#undef OPQ
#undef OPQR
}

// ---------------- kernel 4: logits + log_softmax
__global__ __launch_bounds__(128) void k_out(const float* __restrict__ hs,
                                             const float* __restrict__ out_w,
                                             const float* __restrict__ out_b,
                                             float* __restrict__ out){
    __shared__ float hl[256];
    __shared__ float red0[2];
    __shared__ float red1[2];
    int s = blockIdx.x, tid = threadIdx.x;
    hl[tid]       = hs[(size_t)s * 256 + tid];
    hl[tid + 128] = hs[(size_t)s * 256 + 128 + tid];
    __syncthreads();
    const float4* wr = (const float4*)(out_w + (size_t)tid * 256);
    float acc = out_b[tid];
    #pragma unroll 8
    for (int k = 0; k < 64; ++k){
        float4 v = wr[k];
        acc += v.x * hl[4*k] + v.y * hl[4*k+1] + v.z * hl[4*k+2] + v.w * hl[4*k+3];
    }
    float m = acc;
    #pragma unroll
    for (int off = 32; off; off >>= 1) m = fmaxf(m, __shfl_xor(m, off));
    if ((tid & 63) == 0) red0[tid >> 6] = m;
    __syncthreads();
    float M = fmaxf(red0[0], red0[1]);
    float e = __expf(acc - M);
    float ssum = e;
    #pragma unroll
    for (int off = 32; off; off >>= 1) ssum += __shfl_xor(ssum, off);
    if ((tid & 63) == 0) red1[tid >> 6] = ssum;
    __syncthreads();
    float Z = red1[0] + red1[1];
    out[(size_t)s * 128 + tid] = acc - M - __logf(Z);
}

extern "C" void kernel_launch(void* const* d_in, const int* in_sizes, int n_in,
                              void* d_out, int out_size, void* d_ws, size_t ws_size,
                              hipStream_t stream){
    const int*   word_ixs  = (const int*)  d_in[0];
    const int*   char_ixs  = (const int*)  d_in[1];
    const int*   char_lens = (const int*)  d_in[2];
    const float* word_emb  = (const float*)d_in[3];
    const float* char_emb  = (const float*)d_in[4];
    const float* c_wih     = (const float*)d_in[5];
    const float* c_whh     = (const float*)d_in[6];
    const float* c_bih     = (const float*)d_in[7];
    const float* c_bhh     = (const float*)d_in[8];
    const float* w_wih     = (const float*)d_in[9];
    const float* w_whh     = (const float*)d_in[10];
    const float* w_bih     = (const float*)d_in[11];
    const float* w_bhh     = (const float*)d_in[12];
    const float* out_w     = (const float*)d_in[13];
    const float* out_b     = (const float*)d_in[14];
    float* out = (float*)d_out;

    char* ws = (char*)d_ws;
    const size_t OFF_WX  = 0;                        // 8192*192*4  = 6291456
    const size_t OFF_ZX  = OFF_WX + 6291456;         // 8192*1024*4 = 33554432
    const size_t OFF_HS  = OFF_ZX + 33554432;        // 8192*256*4  = 8388608
    const size_t OFF_WQ  = OFF_HS + 8388608;         // 1024*256    = 262144
    const size_t OFF_FS  = OFF_WQ + 262144;          // 1024*4      = 4096
    float* wx  = (float*)(ws + OFF_WX);
    float* zx  = (float*)(ws + OFF_ZX);
    float* hs  = (float*)(ws + OFF_HS);
    int*   wq  = (int*)  (ws + OFF_WQ);
    float* fsc = (float*)(ws + OFF_FS);

    k_quant<<<dim3(1024), dim3(64),  0, stream>>>(w_whh, wq, fsc);
    k_char <<<dim3(2048), dim3(256), 0, stream>>>(word_ixs, char_ixs, char_lens,
                                                  word_emb, char_emb,
                                                  c_wih, c_whh, c_bih, c_bhh, wx);
    k_proj <<<dim3(1024), dim3(128), 0, stream>>>(wx, w_wih, w_bih, w_bhh, zx);
    k_scan <<<dim3(1),    dim3(512), 0, stream>>>(zx, wq, fsc, hs);
    k_out  <<<dim3(8192), dim3(128), 0, stream>>>(hs, out_w, out_b, out);
}

// Round 6
// 8146.326 us; speedup vs baseline: 1.0667x; 1.0029x over previous
//
#include <hip/hip_runtime.h>
#include <math.h>

#define S_LEN 8192
#define L_CH 12

typedef _Float16 h2 __attribute__((ext_vector_type(2)));
typedef unsigned u32x2 __attribute__((ext_vector_type(2)));

static __device__ __forceinline__ h2 f2h2(float a, float b){
    h2 r; r.x = (_Float16)a; r.y = (_Float16)b; return r;
}

#if defined(__has_builtin)
#if __has_builtin(__builtin_amdgcn_fdot2)
#define HAVE_FDOT2 1
#endif
#if __has_builtin(__builtin_amdgcn_sdot4)
#define HAVE_SDOT4 1
#endif
#if __has_builtin(__builtin_amdgcn_permlane32_swap)
#define HAVE_PLSWAP 1
#endif
#if __has_builtin(__builtin_amdgcn_permlane16_swap)
#define HAVE_PL16SWAP 1
#endif
#endif

static __device__ __forceinline__ float fdot2(h2 a, h2 b, float c){
#ifdef HAVE_FDOT2
    return __builtin_amdgcn_fdot2(a, b, c, false);
#else
    asm("v_dot2_f32_f16 %0, %1, %2, %0" : "+v"(c) : "v"(a), "v"(b));
    return c;
#endif
}

static __device__ __forceinline__ int sdot4(int a, int b, int c){
#ifdef HAVE_SDOT4
    return __builtin_amdgcn_sdot4(a, b, c, false);
#else
    asm("v_dot4_i32_i8 %0, %1, %2, %0" : "+v"(c) : "v"(a), "v"(b));
    return c;
#endif
}

// stage-1 reduce: xor-32 distributing sum. TRUE HW semantics (verified R2/R5):
//   lanes<32  -> sum32(a) = a(l)+a(l^32)
//   lanes>=32 -> sum32(b) = b(l)+b(l^32)
static __device__ __forceinline__ int swap32_sum(int a, int b){
#ifdef HAVE_PLSWAP
    u32x2 r = __builtin_amdgcn_permlane32_swap((unsigned)a, (unsigned)b, false, false);
    return (int)r.x + (int)r.y;
#else
    asm volatile("v_permlane32_swap_b32 %0, %1" : "+v"(a), "+v"(b));
    return a + b;
#endif
}

// stage-2 reduce: xor-16 distributing sum. TRUE HW semantics:
//   (lane&16)==0 -> sum16(a), (lane&16)!=0 -> sum16(b)
static __device__ __forceinline__ int swap16_sum(int a, int b){
#ifdef HAVE_PL16SWAP
    u32x2 r = __builtin_amdgcn_permlane16_swap((unsigned)a, (unsigned)b, false, false);
    return (int)r.x + (int)r.y;
#else
    int sa = a + __builtin_amdgcn_ds_swizzle(a, 0x401F);   // xor16 replicate-sum
    int sb = b + __builtin_amdgcn_ds_swizzle(b, 0x401F);
    return (threadIdx.x & 16) ? sb : sa;
#endif
}

// deliver p's xor-16 partner value to the UPPER row lanes (lane&16 != 0).
static __device__ __forceinline__ float xchg16_to_hi(float p){
#ifdef HAVE_PL16SWAP
    u32x2 r = __builtin_amdgcn_permlane16_swap((unsigned)__float_as_int(p),
                                               (unsigned)__float_as_int(p), false, false);
    return __int_as_float((int)r.x);
#else
    return __int_as_float(__builtin_amdgcn_ds_swizzle(__float_as_int(p), 0x401F));
#endif
}

static __device__ __forceinline__ float fast_sig(float x){
    return 1.0f / (1.0f + __expf(-x));
}
static __device__ __forceinline__ float fast_tanh(float x){
    float ax = fabsf(x);
    float e = __expf(2.0f * ax);
    float t = 1.0f - 2.0f / (e + 1.0f);
    return copysignf(t, x);
}

// ---------------- kernel 0: quantize w_whh (1024x256 f32) to i8 + per-row scale
__global__ __launch_bounds__(64) void k_quant(const float* __restrict__ whh,
                                              int* __restrict__ wq,
                                              float* __restrict__ fsc){
    int r = blockIdx.x;          // 1024 rows
    int k = threadIdx.x;         // 64 lanes, 4 elems each
    float4 v = ((const float4*)(whh + (size_t)r * 256))[k];
    float m = fmaxf(fmaxf(fabsf(v.x), fabsf(v.y)), fmaxf(fabsf(v.z), fabsf(v.w)));
    #pragma unroll
    for (int off = 32; off; off >>= 1) m = fmaxf(m, __shfl_xor(m, off));
    float inv = (m > 0.f) ? (127.0f / m) : 0.0f;
    int q0 = ((int)rintf(v.x * inv)) & 255;
    int q1 = ((int)rintf(v.y * inv)) & 255;
    int q2 = ((int)rintf(v.z * inv)) & 255;
    int q3 = ((int)rintf(v.w * inv)) & 255;
    wq[r * 64 + k] = q0 | (q1 << 8) | (q2 << 16) | (q3 << 24);
    if (k == 0) fsc[r] = m * (1.0f / (127.0f * 127.0f));  // sw * sh, sh = 1/127
}

// ---------------- kernel 1: char LSTM (+ assemble wx = [word_emb | h_char])
__global__ __launch_bounds__(256) void k_char(const int* __restrict__ word_ixs,
                                              const int* __restrict__ char_ixs,
                                              const int* __restrict__ char_lens,
                                              const float* __restrict__ word_emb,
                                              const float* __restrict__ char_emb,
                                              const float* __restrict__ c_wih,
                                              const float* __restrict__ c_whh,
                                              const float* __restrict__ c_bih,
                                              const float* __restrict__ c_bhh,
                                              float* __restrict__ wx){
    __shared__ h2 xh[32];      // x_t as f16 pairs (64 vals)
    __shared__ h2 hh[32];      // h as f16 pairs (64 vals)
    __shared__ float zbuf[256];
    int tid = threadIdx.x;
    h2 wi[32], wh[32];
    {
        const float2* a = (const float2*)(c_wih + (size_t)tid * 64);
        const float2* b = (const float2*)(c_whh + (size_t)tid * 64);
        #pragma unroll
        for (int d = 0; d < 32; ++d){ float2 v = a[d]; wi[d] = f2h2(v.x, v.y); }
        #pragma unroll
        for (int d = 0; d < 32; ++d){ float2 v = b[d]; wh[d] = f2h2(v.x, v.y); }
    }
    float cb = c_bih[tid] + c_bhh[tid];

    for (int w = 0; w < 4; ++w){
        int s = blockIdx.x * 4 + w;
        int len = char_lens[s];
        __syncthreads();
        if (tid < 32) hh[tid] = (h2)0.0f;
        float c_state = 0.f, h_state = 0.f;
        for (int t = 0; t < len; ++t){
            if (tid < 32){
                int ci = char_ixs[s * L_CH + t];
                float2 v = ((const float2*)(char_emb + (size_t)ci * 64))[tid];
                xh[tid] = f2h2(v.x, v.y);
            }
            __syncthreads();
            float acc = cb;
            #pragma unroll
            for (int d = 0; d < 32; ++d) acc = fdot2(wi[d], xh[d], acc);
            #pragma unroll
            for (int d = 0; d < 32; ++d) acc = fdot2(wh[d], hh[d], acc);
            zbuf[tid] = acc;
            __syncthreads();
            if (tid < 64){
                float zi = zbuf[tid], zf = zbuf[64 + tid];
                float zg = zbuf[128 + tid], zo = zbuf[192 + tid];
                c_state = fast_sig(zf) * c_state + fast_sig(zi) * fast_tanh(zg);
                h_state = fast_sig(zo) * fast_tanh(c_state);
                ((_Float16*)hh)[tid] = (_Float16)h_state;
            }
        }
        int wix = word_ixs[s];
        if (tid < 128) wx[(size_t)s * 192 + tid] = word_emb[(size_t)wix * 128 + tid];
        if (tid < 64)  wx[(size_t)s * 192 + 128 + tid] = h_state;
    }
}

// ---------------- kernel 2: zx = wx @ w_wih.T + (w_bih + w_bhh)
__global__ __launch_bounds__(128) void k_proj(const float* __restrict__ wx,
                                              const float* __restrict__ w_wih,
                                              const float* __restrict__ w_bih,
                                              const float* __restrict__ w_bhh,
                                              float* __restrict__ zx){
    __shared__ h2 xl[96];
    int tid = threadIdx.x;
    int jt = blockIdx.x & 7;
    int sc = blockIdx.x >> 3;
    int j  = jt * 128 + tid;
    h2 wreg[96];
    {
        const float2* wr = (const float2*)(w_wih + (size_t)j * 192);
        #pragma unroll
        for (int d = 0; d < 96; ++d){ float2 v = wr[d]; wreg[d] = f2h2(v.x, v.y); }
    }
    float wb = w_bih[j] + w_bhh[j];
    for (int i = 0; i < 64; ++i){
        int s = sc * 64 + i;
        __syncthreads();
        if (tid < 96){
            float2 v = ((const float2*)(wx + (size_t)s * 192))[tid];
            xl[tid] = f2h2(v.x, v.y);
        }
        __syncthreads();
        float acc = wb;
        #pragma unroll
        for (int d = 0; d < 96; ++d) acc = fdot2(wreg[d], xl[d], acc);
        zx[(size_t)s * 1024 + j] = acc;
    }
}

// ---------------- kernel 3: sequential word-LSTM scan (single workgroup)
// Structure identical to R5 (passing). One change: the weight register-class
// constraint ("+v" empty asm) is applied INSIDE the K-loop every iteration.
// R5 evidence (VGPR=88, VALUBusy 82%, no FETCH balloon) => allocator homed the
// 128 weight ints in AGPRs and paid v_accvgpr_read per use. An in-loop VGPR
// def+use makes AGPR homing cost accvgpr_write+read per iter => allocator must
// flip weights to arch VGPRs (pressure ~200 < 256 budget @ 2 waves/EU).
__global__ __attribute__((amdgpu_flat_work_group_size(512,512)))
__attribute__((amdgpu_waves_per_eu(2,2)))
void k_scan(const float* __restrict__ zx,
            const int* __restrict__ wq,
            const float* __restrict__ fsc,
            float* __restrict__ hs){
    __shared__ alignas(16) int hq[2][64];
    int tid  = threadIdx.x;
    int lane = tid & 63;
    int wv   = tid >> 6;
    int s16  = lane & 15;
    int b4   = (lane >> 4) & 1;
    int b5   = lane >> 5;
    int q4   = lane >> 4;            // K-quarter 0..3
    int e0   = (wv << 5) + s16;
    int e1   = e0 + 16;
    int qoff = q4 << 4;              // int offset of my K-quarter within a row

    // post-reduce element + gate-row pair (verified orientation):
    // b5=0 lanes own e0, b5=1 own e1; b4=0 -> (i,g) rows, b4=1 -> (f,o) rows.
    int e  = b5 ? e1 : e0;
    int ra = e + (b4 ? 256 : 0);     // f-row (b4=1) | i-row (b4=0)
    int rb = e + (b4 ? 768 : 512);   // o-row (b4=1) | g-row (b4=0)

#define WLOAD(n, row) \
    int4 w##n##_0, w##n##_1, w##n##_2, w##n##_3; \
    { const int4* p_ = (const int4*)(wq + (size_t)(row) * 64 + qoff); \
      w##n##_0 = p_[0]; w##n##_1 = p_[1]; w##n##_2 = p_[2]; w##n##_3 = p_[3]; }
#define OPQ(v) asm volatile("" : "+v"(v.x), "+v"(v.y), "+v"(v.z), "+v"(v.w))
#define OPQR(n) OPQ(w##n##_0); OPQ(w##n##_1); OPQ(w##n##_2); OPQ(w##n##_3)

    WLOAD(0, e0      ); WLOAD(1, e0 + 256); WLOAD(2, e0 + 512); WLOAD(3, e0 + 768);
    WLOAD(4, e1      ); WLOAD(5, e1 + 256); WLOAD(6, e1 + 512); WLOAD(7, e1 + 768);

    float fa = fsc[ra], fb = fsc[rb];

    if (tid < 64) hq[0][tid] = 0;
    float c_state = 0.f;

    // zx prefetch, 2 steps ahead (rows ra, rb only)
    const float* zc = zx;
    float zA = zc[ra], zB = zc[rb];
    zc += 1024;
    float zA1 = zc[ra], zB1 = zc[rb];

    float* hsp = hs + e;
    __syncthreads();

#define DOTR(acc, n) \
    acc = sdot4(w##n##_0.x, hv0.x, acc); acc = sdot4(w##n##_0.y, hv0.y, acc); \
    acc = sdot4(w##n##_0.z, hv0.z, acc); acc = sdot4(w##n##_0.w, hv0.w, acc); \
    acc = sdot4(w##n##_1.x, hv1.x, acc); acc = sdot4(w##n##_1.y, hv1.y, acc); \
    acc = sdot4(w##n##_1.z, hv1.z, acc); acc = sdot4(w##n##_1.w, hv1.w, acc); \
    acc = sdot4(w##n##_2.x, hv2.x, acc); acc = sdot4(w##n##_2.y, hv2.y, acc); \
    acc = sdot4(w##n##_2.z, hv2.z, acc); acc = sdot4(w##n##_2.w, hv2.w, acc); \
    acc = sdot4(w##n##_3.x, hv3.x, acc); acc = sdot4(w##n##_3.y, hv3.y, acc); \
    acc = sdot4(w##n##_3.z, hv3.z, acc); acc = sdot4(w##n##_3.w, hv3.w, acc)

    #pragma unroll 2
    for (int t = 0; t < S_LEN; ++t){
        float curA = zA, curB = zB;
        zA = zA1; zB = zB1;
        if (t < S_LEN - 2) zc += 1024;      // clamp: avoid OOB prefetch
        zA1 = zc[ra]; zB1 = zc[rb];

        // read my K-quarter of h: 4 x ds_read_b128 (same addr within 16-lane group)
        const int4* hp = (const int4*)((const int*)hq[t & 1] + qoff);
        int4 hv0 = hp[0], hv1 = hp[1], hv2 = hp[2], hv3 = hp[3];

        // IN-LOOP register-class pin: weights must materialize in arch VGPRs
        // here, every iteration (zero instructions emitted).
        OPQR(0); OPQR(1); OPQR(2); OPQR(3); OPQR(4); OPQR(5); OPQR(6); OPQR(7);

        int a0 = 0, a1 = 0, a2 = 0, a3 = 0, a4 = 0, a5 = 0, a6 = 0, a7 = 0;
        DOTR(a0, 0); DOTR(a4, 4);
        DOTR(a1, 1); DOTR(a5, 5);
        DOTR(a2, 2); DOTR(a6, 6);
        DOTR(a3, 3); DOTR(a7, 7);

        // stage 1: b5=0 lanes -> e0 sums, b5=1 -> e1 sums
        int si = swap32_sum(a0, a4);
        int sf = swap32_sum(a1, a5);
        int sg = swap32_sum(a2, a6);
        int so = swap32_sum(a3, a7);
        // stage 2: full-K sums, distributed: b4=0 -> (i,g), b4=1 -> (f,o)
        int red_a = swap16_sum(si, sf);
        int red_b = swap16_sum(sg, so);

        float va = fmaf((float)red_a, fa, curA);   // z_i (b4=0) | z_f (b4=1)
        float vb = fmaf((float)red_b, fb, curB);   // z_g (b4=0) | z_o (b4=1)

        float sa = fast_sig(va);                   // sig(i) | sig(f)
        float p  = sa * fast_tanh(vb);             // i*tanh(g)  (valid on b4=0)
        float sb = fast_sig(vb);                   // sig(o)     (valid on b4=1)
        float pr = xchg16_to_hi(p);                // b4=1 lanes get partner's p

        c_state = sa * c_state + pr;               // valid on b4=1 lanes
        float h = sb * fast_tanh(c_state);

        if (b4 == 1){
            hsp[0] = h;
            int q = (int)rintf(h * 127.0f);
            ((signed char*)hq[(t + 1) & 1])[e] = (signed char)q;
        }
        hsp += 256;
        __syncthreads();
    }
#undef DOTR
#undef WLOAD
#undef OPQ
#undef OPQR
}

// ---------------- kernel 4: logits + log_softmax
__global__ __launch_bounds__(128) void k_out(const float* __restrict__ hs,
                                             const float* __restrict__ out_w,
                                             const float* __restrict__ out_b,
                                             float* __restrict__ out){
    __shared__ float hl[256];
    __shared__ float red0[2];
    __shared__ float red1[2];
    int s = blockIdx.x, tid = threadIdx.x;
    hl[tid]       = hs[(size_t)s * 256 + tid];
    hl[tid + 128] = hs[(size_t)s * 256 + 128 + tid];
    __syncthreads();
    const float4* wr = (const float4*)(out_w + (size_t)tid * 256);
    float acc = out_b[tid];
    #pragma unroll 8
    for (int k = 0; k < 64; ++k){
        float4 v = wr[k];
        acc += v.x * hl[4*k] + v.y * hl[4*k+1] + v.z * hl[4*k+2] + v.w * hl[4*k+3];
    }
    float m = acc;
    #pragma unroll
    for (int off = 32; off; off >>= 1) m = fmaxf(m, __shfl_xor(m, off));
    if ((tid & 63) == 0) red0[tid >> 6] = m;
    __syncthreads();
    float M = fmaxf(red0[0], red0[1]);
    float e = __expf(acc - M);
    float ssum = e;
    #pragma unroll
    for (int off = 32; off; off >>= 1) ssum += __shfl_xor(ssum, off);
    if ((tid & 63) == 0) red1[tid >> 6] = ssum;
    __syncthreads();
    float Z = red1[0] + red1[1];
    out[(size_t)s * 128 + tid] = acc - M - __logf(Z);
}

extern "C" void kernel_launch(void* const* d_in, const int* in_sizes, int n_in,
                              void* d_out, int out_size, void* d_ws, size_t ws_size,
                              hipStream_t stream){
    const int*   word_ixs  = (const int*)  d_in[0];
    const int*   char_ixs  = (const int*)  d_in[1];
    const int*   char_lens = (const int*)  d_in[2];
    const float* word_emb  = (const float*)d_in[3];
    const float* char_emb  = (const float*)d_in[4];
    const float* c_wih     = (const float*)d_in[5];
    const float* c_whh     = (const float*)d_in[6];
    const float* c_bih     = (const float*)d_in[7];
    const float* c_bhh     = (const float*)d_in[8];
    const float* w_wih     = (const float*)d_in[9];
    const float* w_whh     = (const float*)d_in[10];
    const float* w_bih     = (const float*)d_in[11];
    const float* w_bhh     = (const float*)d_in[12];
    const float* out_w     = (const float*)d_in[13];
    const float* out_b     = (const float*)d_in[14];
    float* out = (float*)d_out;

    char* ws = (char*)d_ws;
    const size_t OFF_WX  = 0;                        // 8192*192*4  = 6291456
    const size_t OFF_ZX  = OFF_WX + 6291456;         // 8192*1024*4 = 33554432
    const size_t OFF_HS  = OFF_ZX + 33554432;        // 8192*256*4  = 8388608
    const size_t OFF_WQ  = OFF_HS + 8388608;         // 1024*256    = 262144
    const size_t OFF_FS  = OFF_WQ + 262144;          // 1024*4      = 4096
    float* wx  = (float*)(ws + OFF_WX);
    float* zx  = (float*)(ws + OFF_ZX);
    float* hs  = (float*)(ws + OFF_HS);
    int*   wq  = (int*)  (ws + OFF_WQ);
    float* fsc = (float*)(ws + OFF_FS);

    k_quant<<<dim3(1024), dim3(64),  0, stream>>>(w_whh, wq, fsc);
    k_char <<<dim3(2048), dim3(256), 0, stream>>>(word_ixs, char_ixs, char_lens,
                                                  word_emb, char_emb,
                                                  c_wih, c_whh, c_bih, c_bhh, wx);
    k_proj <<<dim3(1024), dim3(128), 0, stream>>>(wx, w_wih, w_bih, w_bhh, zx);
    k_scan <<<dim3(1),    dim3(512), 0, stream>>>(zx, wq, fsc, hs);
    k_out  <<<dim3(8192), dim3(128), 0, stream>>>(hs, out_w, out_b, out);
}

// Round 7
// 8025.860 us; speedup vs baseline: 1.0827x; 1.0150x over previous
//
#include <hip/hip_runtime.h>
#include <math.h>

#define S_LEN 8192
#define L_CH 12

typedef _Float16 h2 __attribute__((ext_vector_type(2)));
typedef int iv4 __attribute__((ext_vector_type(4)));

static __device__ __forceinline__ h2 f2h2(float a, float b){
    h2 r; r.x = (_Float16)a; r.y = (_Float16)b; return r;
}

#if defined(__has_builtin)
#if __has_builtin(__builtin_amdgcn_fdot2)
#define HAVE_FDOT2 1
#endif
#endif

static __device__ __forceinline__ float fdot2(h2 a, h2 b, float c){
#ifdef HAVE_FDOT2
    return __builtin_amdgcn_fdot2(a, b, c, false);
#else
    asm("v_dot2_f32_f16 %0, %1, %2, %0" : "+v"(c) : "v"(a), "v"(b));
    return c;
#endif
}

static __device__ __forceinline__ float fast_sig(float x){
    return 1.0f / (1.0f + __expf(-x));
}
static __device__ __forceinline__ float fast_tanh(float x){
    float ax = fabsf(x);
    float e = __expf(2.0f * ax);
    float t = 1.0f - 2.0f / (e + 1.0f);
    return copysignf(t, x);
}

// ---------------- kernel 0: quantize w_whh (1024x256 f32) to i8 row-scaled AND
// pack into MFMA A-fragment order for mfma_i32_16x16x64_i8.
// Row r: gate g = r>>8, element e = r&255 -> wave w = e>>5, half h = (e>>4)&1,
// rowin16 = e&15, tile tIdx = g*2+h (wave-local).
// A-frag mapping (per lane dl of the wave): row = dl&15, k-slice s, lane-group
// lk = dl>>4, k = s*64 + lk*16 + d*4 + b  (d = dword 0..3 within iv4, b = byte).
// Source lane kk covers k = kk*4 + b  ->  s = kk>>4, lk = (kk&15)>>2, d = kk&3.
__global__ __launch_bounds__(64) void k_pack(const float* __restrict__ whh,
                                             int* __restrict__ wpack,
                                             float* __restrict__ fsc){
    int r  = blockIdx.x;          // 1024 rows
    int kk = threadIdx.x;         // 64 lanes, 4 consecutive k each
    float4 v = ((const float4*)(whh + (size_t)r * 256))[kk];
    float m = fmaxf(fmaxf(fabsf(v.x), fabsf(v.y)), fmaxf(fabsf(v.z), fabsf(v.w)));
    #pragma unroll
    for (int off = 32; off; off >>= 1) m = fmaxf(m, __shfl_xor(m, off));
    float inv = (m > 0.f) ? (127.0f / m) : 0.0f;
    int q0 = ((int)rintf(v.x * inv)) & 255;
    int q1 = ((int)rintf(v.y * inv)) & 255;
    int q2 = ((int)rintf(v.z * inv)) & 255;
    int q3 = ((int)rintf(v.w * inv)) & 255;
    int q  = q0 | (q1 << 8) | (q2 << 16) | (q3 << 24);
    if (kk == 0) fsc[r] = m * (1.0f / (127.0f * 127.0f));  // sw * sh, sh = 1/127

    int g = r >> 8;
    int e = r & 255;
    int w = e >> 5;
    int h = (e >> 4) & 1;
    int rowin16 = e & 15;
    int tIdx = g * 2 + h;
    int s  = kk >> 4;
    int lk = (kk & 15) >> 2;
    int d  = kk & 3;
    int dl = (lk << 4) | rowin16;                    // destination lane
    wpack[(size_t)(w * 64 + dl) * 128 + tIdx * 16 + s * 4 + d] = q;
}

// ---------------- kernel 1: char LSTM (+ assemble wx = [word_emb | h_char])
__global__ __launch_bounds__(256) void k_char(const int* __restrict__ word_ixs,
                                              const int* __restrict__ char_ixs,
                                              const int* __restrict__ char_lens,
                                              const float* __restrict__ word_emb,
                                              const float* __restrict__ char_emb,
                                              const float* __restrict__ c_wih,
                                              const float* __restrict__ c_whh,
                                              const float* __restrict__ c_bih,
                                              const float* __restrict__ c_bhh,
                                              float* __restrict__ wx){
    __shared__ h2 xh[32];      // x_t as f16 pairs (64 vals)
    __shared__ h2 hh[32];      // h as f16 pairs (64 vals)
    __shared__ float zbuf[256];
    int tid = threadIdx.x;
    h2 wi[32], wh[32];
    {
        const float2* a = (const float2*)(c_wih + (size_t)tid * 64);
        const float2* b = (const float2*)(c_whh + (size_t)tid * 64);
        #pragma unroll
        for (int d = 0; d < 32; ++d){ float2 v = a[d]; wi[d] = f2h2(v.x, v.y); }
        #pragma unroll
        for (int d = 0; d < 32; ++d){ float2 v = b[d]; wh[d] = f2h2(v.x, v.y); }
    }
    float cb = c_bih[tid] + c_bhh[tid];

    for (int w = 0; w < 4; ++w){
        int s = blockIdx.x * 4 + w;
        int len = char_lens[s];
        __syncthreads();
        if (tid < 32) hh[tid] = (h2)0.0f;
        float c_state = 0.f, h_state = 0.f;
        for (int t = 0; t < len; ++t){
            if (tid < 32){
                int ci = char_ixs[s * L_CH + t];
                float2 v = ((const float2*)(char_emb + (size_t)ci * 64))[tid];
                xh[tid] = f2h2(v.x, v.y);
            }
            __syncthreads();
            float acc = cb;
            #pragma unroll
            for (int d = 0; d < 32; ++d) acc = fdot2(wi[d], xh[d], acc);
            #pragma unroll
            for (int d = 0; d < 32; ++d) acc = fdot2(wh[d], hh[d], acc);
            zbuf[tid] = acc;
            __syncthreads();
            if (tid < 64){
                float zi = zbuf[tid], zf = zbuf[64 + tid];
                float zg = zbuf[128 + tid], zo = zbuf[192 + tid];
                c_state = fast_sig(zf) * c_state + fast_sig(zi) * fast_tanh(zg);
                h_state = fast_sig(zo) * fast_tanh(c_state);
                ((_Float16*)hh)[tid] = (_Float16)h_state;
            }
        }
        int wix = word_ixs[s];
        if (tid < 128) wx[(size_t)s * 192 + tid] = word_emb[(size_t)wix * 128 + tid];
        if (tid < 64)  wx[(size_t)s * 192 + 128 + tid] = h_state;
    }
}

// ---------------- kernel 2: zx = wx @ w_wih.T + (w_bih + w_bhh)
__global__ __launch_bounds__(128) void k_proj(const float* __restrict__ wx,
                                              const float* __restrict__ w_wih,
                                              const float* __restrict__ w_bih,
                                              const float* __restrict__ w_bhh,
                                              float* __restrict__ zx){
    __shared__ h2 xl[96];
    int tid = threadIdx.x;
    int jt = blockIdx.x & 7;
    int sc = blockIdx.x >> 3;
    int j  = jt * 128 + tid;
    h2 wreg[96];
    {
        const float2* wr = (const float2*)(w_wih + (size_t)j * 192);
        #pragma unroll
        for (int d = 0; d < 96; ++d){ float2 v = wr[d]; wreg[d] = f2h2(v.x, v.y); }
    }
    float wb = w_bih[j] + w_bhh[j];
    for (int i = 0; i < 64; ++i){
        int s = sc * 64 + i;
        __syncthreads();
        if (tid < 96){
            float2 v = ((const float2*)(wx + (size_t)s * 192))[tid];
            xl[tid] = f2h2(v.x, v.y);
        }
        __syncthreads();
        float acc = wb;
        #pragma unroll
        for (int d = 0; d < 96; ++d) acc = fdot2(wreg[d], xl[d], acc);
        zx[(size_t)s * 1024 + j] = acc;
    }
}

// ---------------- kernel 3: sequential word-LSTM scan (single workgroup, MFMA)
// 512 threads = 8 waves. Wave w owns elements [32w, 32w+32); its 128 gate-rows
// are packed (k_pack) as 8 A-tiles = 4 gates x 2 halves. Per step:
//   B-frag = h (i8) broadcast into all 16 cols -> 4 ds_read_b128 from hq.
//   32 x mfma_i32_16x16x64_i8 per wave (8 tiles x 4 K-slices), D = W.h (all
//   cols identical; rows: rowin16 = (lane>>4)*4 + reg  [C/D layout, m89]).
//   Lane-local gates: lane (p = lane&15, lk = lane>>4) handles element
//   e = 32w + (j>>2)*16 + lk*4 + (j&3), j = p&7 (2x redundant: p and p+8).
//   D-register de-replication via static-index cndmask tree (rule #20 safe).
//   One barrier per step; h written back as i8 to hq (double-buffered).
__global__ __attribute__((amdgpu_flat_work_group_size(512,512)))
__attribute__((amdgpu_waves_per_eu(2,2)))
void k_scan(const float* __restrict__ zx,
            const int* __restrict__ wpack,
            const float* __restrict__ fsc,
            float* __restrict__ hs){
    __shared__ alignas(16) int hq[2][64];   // 256 x i8 each, double-buffered
    int tid  = threadIdx.x;
    int lane = tid & 63;
    int w    = tid >> 6;
    int lk   = lane >> 4;
    int p    = lane & 15;
    int j    = p & 7;
    int h_   = j >> 2;
    int r_   = j & 3;
    int e    = (w << 5) + (h_ << 4) + (lk << 2) + r_;
    bool selh = (h_ != 0);
    bool selr1 = (r_ & 1) != 0;
    bool selr2 = (r_ & 2) != 0;

    // load my 32 A-frags (128 dwords); AGPR homing is fine (MFMA reads AGPRs)
    iv4 A[8][4];
    {
        const iv4* wp = (const iv4*)(wpack + (size_t)((w << 6) + lane) * 128);
        #pragma unroll
        for (int t = 0; t < 8; ++t)
            #pragma unroll
            for (int s = 0; s < 4; ++s) A[t][s] = wp[t * 4 + s];
    }
    float fs0 = fsc[e], fs1 = fsc[256 + e], fs2 = fsc[512 + e], fs3 = fsc[768 + e];

    if (tid < 64) hq[0][tid] = 0;
    float c_state = 0.f;

    // zx for my element's 4 gate rows, prefetched 2 steps ahead
    const float* zr = zx + e;
    float z0 = zr[0], z1 = zr[256], z2 = zr[512], z3 = zr[768];
    float y0, y1, y2, y3;
    { const float* zn = zr + 1024; y0 = zn[0]; y1 = zn[256]; y2 = zn[512]; y3 = zn[768]; }

    __syncthreads();

    #pragma unroll 1
    for (int t = 0; t < S_LEN; ++t){
        int cur = t & 1;
        // B-frags: lane group lk reads h bytes [s*64 + lk*16 .. +15]
        const iv4* hb = (const iv4*)hq[cur];
        iv4 B0 = hb[lk], B1 = hb[4 + lk], B2 = hb[8 + lk], B3 = hb[12 + lk];

        iv4 D[8];
        #pragma unroll
        for (int q = 0; q < 8; ++q){
            iv4 z4 = {0, 0, 0, 0};
            D[q] = __builtin_amdgcn_mfma_i32_16x16x64_i8(A[q][0], B0, z4,   0, 0, 0);
            D[q] = __builtin_amdgcn_mfma_i32_16x16x64_i8(A[q][1], B1, D[q], 0, 0, 0);
            D[q] = __builtin_amdgcn_mfma_i32_16x16x64_i8(A[q][2], B2, D[q], 0, 0, 0);
            D[q] = __builtin_amdgcn_mfma_i32_16x16x64_i8(A[q][3], B3, D[q], 0, 0, 0);
        }

        float zc0 = z0, zc1 = z1, zc2 = z2, zc3 = z3;
        z0 = y0; z1 = y1; z2 = y2; z3 = y3;
        {
            int tn = (t + 2 < S_LEN) ? (t + 2) : (S_LEN - 1);
            const float* zn = zx + (size_t)tn * 1024 + e;
            y0 = zn[0]; y1 = zn[256]; y2 = zn[512]; y3 = zn[768];
        }

        // de-replicate: pick my (h_, r_) result from each gate's tile pair
        int d0, d1, d2, d3;
#define GSEL(dst, g) { \
        int v0 = selh ? D[2*(g)+1][0] : D[2*(g)][0]; \
        int v1 = selh ? D[2*(g)+1][1] : D[2*(g)][1]; \
        int v2 = selh ? D[2*(g)+1][2] : D[2*(g)][2]; \
        int v3 = selh ? D[2*(g)+1][3] : D[2*(g)][3]; \
        int va = selr1 ? v1 : v0; \
        int vb = selr1 ? v3 : v2; \
        dst = selr2 ? vb : va; }
        GSEL(d0, 0) GSEL(d1, 1) GSEL(d2, 2) GSEL(d3, 3)
#undef GSEL

        float zi = fmaf((float)d0, fs0, zc0);
        float zf = fmaf((float)d1, fs1, zc1);
        float zg = fmaf((float)d2, fs2, zc2);
        float zo = fmaf((float)d3, fs3, zc3);

        float pp = fast_sig(zi) * fast_tanh(zg);
        c_state  = fast_sig(zf) * c_state + pp;
        float hv = fast_sig(zo) * fast_tanh(c_state);

        if (p < 8){
            hs[(size_t)t * 256 + e] = hv;
            int qv = (int)rintf(hv * 127.0f);
            ((signed char*)hq[cur ^ 1])[e] = (signed char)qv;
        }
        __syncthreads();
    }
}

// ---------------- kernel 4: logits + log_softmax
__global__ __launch_bounds__(128) void k_out(const float* __restrict__ hs,
                                             const float* __restrict__ out_w,
                                             const float* __restrict__ out_b,
                                             float* __restrict__ out){
    __shared__ float hl[256];
    __shared__ float red0[2];
    __shared__ float red1[2];
    int s = blockIdx.x, tid = threadIdx.x;
    hl[tid]       = hs[(size_t)s * 256 + tid];
    hl[tid + 128] = hs[(size_t)s * 256 + 128 + tid];
    __syncthreads();
    const float4* wr = (const float4*)(out_w + (size_t)tid * 256);
    float acc = out_b[tid];
    #pragma unroll 8
    for (int k = 0; k < 64; ++k){
        float4 v = wr[k];
        acc += v.x * hl[4*k] + v.y * hl[4*k+1] + v.z * hl[4*k+2] + v.w * hl[4*k+3];
    }
    float m = acc;
    #pragma unroll
    for (int off = 32; off; off >>= 1) m = fmaxf(m, __shfl_xor(m, off));
    if ((tid & 63) == 0) red0[tid >> 6] = m;
    __syncthreads();
    float M = fmaxf(red0[0], red0[1]);
    float e = __expf(acc - M);
    float ssum = e;
    #pragma unroll
    for (int off = 32; off; off >>= 1) ssum += __shfl_xor(ssum, off);
    if ((tid & 63) == 0) red1[tid >> 6] = ssum;
    __syncthreads();
    float Z = red1[0] + red1[1];
    out[(size_t)s * 128 + tid] = acc - M - __logf(Z);
}

extern "C" void kernel_launch(void* const* d_in, const int* in_sizes, int n_in,
                              void* d_out, int out_size, void* d_ws, size_t ws_size,
                              hipStream_t stream){
    const int*   word_ixs  = (const int*)  d_in[0];
    const int*   char_ixs  = (const int*)  d_in[1];
    const int*   char_lens = (const int*)  d_in[2];
    const float* word_emb  = (const float*)d_in[3];
    const float* char_emb  = (const float*)d_in[4];
    const float* c_wih     = (const float*)d_in[5];
    const float* c_whh     = (const float*)d_in[6];
    const float* c_bih     = (const float*)d_in[7];
    const float* c_bhh     = (const float*)d_in[8];
    const float* w_wih     = (const float*)d_in[9];
    const float* w_whh     = (const float*)d_in[10];
    const float* w_bih     = (const float*)d_in[11];
    const float* w_bhh     = (const float*)d_in[12];
    const float* out_w     = (const float*)d_in[13];
    const float* out_b     = (const float*)d_in[14];
    float* out = (float*)d_out;

    char* ws = (char*)d_ws;
    const size_t OFF_WX  = 0;                        // 8192*192*4  = 6291456
    const size_t OFF_ZX  = OFF_WX + 6291456;         // 8192*1024*4 = 33554432
    const size_t OFF_HS  = OFF_ZX + 33554432;        // 8192*256*4  = 8388608
    const size_t OFF_WQ  = OFF_HS + 8388608;         // 1024*256    = 262144
    const size_t OFF_FS  = OFF_WQ + 262144;          // 1024*4      = 4096
    float* wx    = (float*)(ws + OFF_WX);
    float* zx    = (float*)(ws + OFF_ZX);
    float* hs    = (float*)(ws + OFF_HS);
    int*   wpack = (int*)  (ws + OFF_WQ);
    float* fsc   = (float*)(ws + OFF_FS);

    k_pack <<<dim3(1024), dim3(64),  0, stream>>>(w_whh, wpack, fsc);
    k_char <<<dim3(2048), dim3(256), 0, stream>>>(word_ixs, char_ixs, char_lens,
                                                  word_emb, char_emb,
                                                  c_wih, c_whh, c_bih, c_bhh, wx);
    k_proj <<<dim3(1024), dim3(128), 0, stream>>>(wx, w_wih, w_bih, w_bhh, zx);
    k_scan <<<dim3(1),    dim3(512), 0, stream>>>(zx, wpack, fsc, hs);
    k_out  <<<dim3(8192), dim3(128), 0, stream>>>(hs, out_w, out_b, out);
}

// Round 8
// 7219.588 us; speedup vs baseline: 1.2036x; 1.1117x over previous
//
#include <hip/hip_runtime.h>
#include <math.h>

#define S_LEN 8192
#define L_CH 12

typedef _Float16 h2 __attribute__((ext_vector_type(2)));
typedef int iv4 __attribute__((ext_vector_type(4)));

static __device__ __forceinline__ h2 f2h2(float a, float b){
    h2 r; r.x = (_Float16)a; r.y = (_Float16)b; return r;
}

#if defined(__has_builtin)
#if __has_builtin(__builtin_amdgcn_fdot2)
#define HAVE_FDOT2 1
#endif
#endif

static __device__ __forceinline__ float fdot2(h2 a, h2 b, float c){
#ifdef HAVE_FDOT2
    return __builtin_amdgcn_fdot2(a, b, c, false);
#else
    asm("v_dot2_f32_f16 %0, %1, %2, %0" : "+v"(c) : "v"(a), "v"(b));
    return c;
#endif
}

static __device__ __forceinline__ float fast_sig(float x){
    return 1.0f / (1.0f + __expf(-x));
}
static __device__ __forceinline__ float fast_tanh(float x){
    float ax = fabsf(x);
    float e = __expf(2.0f * ax);
    float t = 1.0f - 2.0f / (e + 1.0f);
    return copysignf(t, x);
}

// raw per-step barrier: LDS-visibility only (no vmcnt drain).
// Steps are LDS/VALU/MFMA-only, so skipping the vmem drain is safe; staged
// global loads stay in flight across barriers (the whole point).
#define BAR() asm volatile("s_waitcnt lgkmcnt(0)\n\ts_barrier" ::: "memory")

// ---------------- kernel 0: quantize w_whh (1024x256 f32) to i8 row-scaled AND
// pack into MFMA A-fragment order for mfma_i32_16x16x64_i8.
// Row r: gate g = r>>8, element e = r&255 -> wave w = e>>5, half h = (e>>4)&1,
// rowin16 = e&15, tile tIdx = g*2+h (wave-local).
// A-frag mapping (per lane dl of the wave): row = dl&15, k-slice s, lane-group
// lk = dl>>4, k = s*64 + lk*16 + d*4 + b  (d = dword 0..3 within iv4, b = byte).
// Source lane kk covers k = kk*4 + b  ->  s = kk>>4, lk = (kk&15)>>2, d = kk&3.
__global__ __launch_bounds__(64) void k_pack(const float* __restrict__ whh,
                                             int* __restrict__ wpack,
                                             float* __restrict__ fsc){
    int r  = blockIdx.x;          // 1024 rows
    int kk = threadIdx.x;         // 64 lanes, 4 consecutive k each
    float4 v = ((const float4*)(whh + (size_t)r * 256))[kk];
    float m = fmaxf(fmaxf(fabsf(v.x), fabsf(v.y)), fmaxf(fabsf(v.z), fabsf(v.w)));
    #pragma unroll
    for (int off = 32; off; off >>= 1) m = fmaxf(m, __shfl_xor(m, off));
    float inv = (m > 0.f) ? (127.0f / m) : 0.0f;
    int q0 = ((int)rintf(v.x * inv)) & 255;
    int q1 = ((int)rintf(v.y * inv)) & 255;
    int q2 = ((int)rintf(v.z * inv)) & 255;
    int q3 = ((int)rintf(v.w * inv)) & 255;
    int q  = q0 | (q1 << 8) | (q2 << 16) | (q3 << 24);
    if (kk == 0) fsc[r] = m * (1.0f / (127.0f * 127.0f));  // sw * sh, sh = 1/127

    int g = r >> 8;
    int e = r & 255;
    int w = e >> 5;
    int h = (e >> 4) & 1;
    int rowin16 = e & 15;
    int tIdx = g * 2 + h;
    int s  = kk >> 4;
    int lk = (kk & 15) >> 2;
    int d  = kk & 3;
    int dl = (lk << 4) | rowin16;                    // destination lane
    wpack[(size_t)(w * 64 + dl) * 128 + tIdx * 16 + s * 4 + d] = q;
}

// ---------------- kernel 1: char LSTM (+ assemble wx = [word_emb | h_char])
__global__ __launch_bounds__(256) void k_char(const int* __restrict__ word_ixs,
                                              const int* __restrict__ char_ixs,
                                              const int* __restrict__ char_lens,
                                              const float* __restrict__ word_emb,
                                              const float* __restrict__ char_emb,
                                              const float* __restrict__ c_wih,
                                              const float* __restrict__ c_whh,
                                              const float* __restrict__ c_bih,
                                              const float* __restrict__ c_bhh,
                                              float* __restrict__ wx){
    __shared__ h2 xh[32];      // x_t as f16 pairs (64 vals)
    __shared__ h2 hh[32];      // h as f16 pairs (64 vals)
    __shared__ float zbuf[256];
    int tid = threadIdx.x;
    h2 wi[32], wh[32];
    {
        const float2* a = (const float2*)(c_wih + (size_t)tid * 64);
        const float2* b = (const float2*)(c_whh + (size_t)tid * 64);
        #pragma unroll
        for (int d = 0; d < 32; ++d){ float2 v = a[d]; wi[d] = f2h2(v.x, v.y); }
        #pragma unroll
        for (int d = 0; d < 32; ++d){ float2 v = b[d]; wh[d] = f2h2(v.x, v.y); }
    }
    float cb = c_bih[tid] + c_bhh[tid];

    for (int w = 0; w < 4; ++w){
        int s = blockIdx.x * 4 + w;
        int len = char_lens[s];
        __syncthreads();
        if (tid < 32) hh[tid] = (h2)0.0f;
        float c_state = 0.f, h_state = 0.f;
        for (int t = 0; t < len; ++t){
            if (tid < 32){
                int ci = char_ixs[s * L_CH + t];
                float2 v = ((const float2*)(char_emb + (size_t)ci * 64))[tid];
                xh[tid] = f2h2(v.x, v.y);
            }
            __syncthreads();
            float acc = cb;
            #pragma unroll
            for (int d = 0; d < 32; ++d) acc = fdot2(wi[d], xh[d], acc);
            #pragma unroll
            for (int d = 0; d < 32; ++d) acc = fdot2(wh[d], hh[d], acc);
            zbuf[tid] = acc;
            __syncthreads();
            if (tid < 64){
                float zi = zbuf[tid], zf = zbuf[64 + tid];
                float zg = zbuf[128 + tid], zo = zbuf[192 + tid];
                c_state = fast_sig(zf) * c_state + fast_sig(zi) * fast_tanh(zg);
                h_state = fast_sig(zo) * fast_tanh(c_state);
                ((_Float16*)hh)[tid] = (_Float16)h_state;
            }
        }
        int wix = word_ixs[s];
        if (tid < 128) wx[(size_t)s * 192 + tid] = word_emb[(size_t)wix * 128 + tid];
        if (tid < 64)  wx[(size_t)s * 192 + 128 + tid] = h_state;
    }
}

// ---------------- kernel 2: zx = wx @ w_wih.T + (w_bih + w_bhh)
__global__ __launch_bounds__(128) void k_proj(const float* __restrict__ wx,
                                              const float* __restrict__ w_wih,
                                              const float* __restrict__ w_bih,
                                              const float* __restrict__ w_bhh,
                                              float* __restrict__ zx){
    __shared__ h2 xl[96];
    int tid = threadIdx.x;
    int jt = blockIdx.x & 7;
    int sc = blockIdx.x >> 3;
    int j  = jt * 128 + tid;
    h2 wreg[96];
    {
        const float2* wr = (const float2*)(w_wih + (size_t)j * 192);
        #pragma unroll
        for (int d = 0; d < 96; ++d){ float2 v = wr[d]; wreg[d] = f2h2(v.x, v.y); }
    }
    float wb = w_bih[j] + w_bhh[j];
    for (int i = 0; i < 64; ++i){
        int s = sc * 64 + i;
        __syncthreads();
        if (tid < 96){
            float2 v = ((const float2*)(wx + (size_t)s * 192))[tid];
            xl[tid] = f2h2(v.x, v.y);
        }
        __syncthreads();
        float acc = wb;
        #pragma unroll
        for (int d = 0; d < 96; ++d) acc = fdot2(wreg[d], xl[d], acc);
        zx[(size_t)s * 1024 + j] = acc;
    }
}

// ---------------- kernel 3: sequential word-LSTM scan (single workgroup, MFMA)
// R7 core (MFMA i8, GSEL de-rep, verified absmax 0.03125) + superstep staging:
//   - zx served from LDS zxl[2][8192]; superstep k+2's 32 KB is loaded into
//     registers at the END of superstep k and ds-written at the END of k+1
//     (issue-early / write-late: ~900 cy HBM latency hides under 8 steps).
//   - h history buffered in LDS hsb[2048], flushed once per superstep.
//   - per-step barrier is raw lgkmcnt(0)+s_barrier: NO vmcnt drain, so the
//     staged loads stay in flight across barriers. Steps have zero VMEM.
__global__ __attribute__((amdgpu_flat_work_group_size(512,512)))
void k_scan(const float* __restrict__ zx,
            const int* __restrict__ wpack,
            const float* __restrict__ fsc,
            float* __restrict__ hs){
    __shared__ float zxl[2][8192];          // 64 KB: zx double-buffer (8 steps each)
    __shared__ float hsb[2048];             // 8 KB: h history, one superstep
    __shared__ alignas(16) int hq[2][64];   // 256 x i8, double-buffered
    int tid  = threadIdx.x;
    int lane = tid & 63;
    int w    = tid >> 6;
    int lk   = lane >> 4;
    int p    = lane & 15;
    int j    = p & 7;
    int h_   = j >> 2;
    int r_   = j & 3;
    int e    = (w << 5) + (h_ << 4) + (lk << 2) + r_;
    bool selh  = (h_ != 0);
    bool selr1 = (r_ & 1) != 0;
    bool selr2 = (r_ & 2) != 0;

    // 32 A-frags (128 dwords); AGPR homing fine (MFMA reads AGPRs directly)
    iv4 A[8][4];
    {
        const iv4* wp = (const iv4*)(wpack + (size_t)((w << 6) + lane) * 128);
        #pragma unroll
        for (int t = 0; t < 8; ++t)
            #pragma unroll
            for (int s = 0; s < 4; ++s) A[t][s] = wp[t * 4 + s];
    }
    float fs0 = fsc[e], fs1 = fsc[256 + e], fs2 = fsc[512 + e], fs3 = fsc[768 + e];

    const float4* zp4 = (const float4*)zx;           // superstep m = zp4 + m*2048
    // prologue: stage superstep 0 directly; preload superstep 1 into regs
    {
        float4 sa = zp4[tid], sb = zp4[512 + tid], sc_ = zp4[1024 + tid], sd = zp4[1536 + tid];
        float4* zl0 = (float4*)zxl[0];
        zl0[tid] = sa; zl0[512 + tid] = sb; zl0[1024 + tid] = sc_; zl0[1536 + tid] = sd;
    }
    float4 ga = zp4[2048 + tid], gb = zp4[2048 + 512 + tid],
           gc = zp4[2048 + 1024 + tid], gd = zp4[2048 + 1536 + tid];

    if (tid < 64) hq[0][tid] = 0;
    float c_state = 0.f;
    __syncthreads();    // full drain once (prologue only)

    #pragma unroll 1
    for (int ss = 0; ss < 1024; ++ss){
        int cur = ss & 1;
        // flush previous superstep's h history (uniform branch)
        if (ss > 0){
            float4 hv4 = ((const float4*)hsb)[tid];
            ((float4*)(hs + (size_t)(ss - 1) * 2048))[tid] = hv4;
        }
        BAR();   // flush reads done before steps overwrite hsb; zxl[cur] ready

        #pragma unroll 2
        for (int s = 0; s < 8; ++s){
            int t01 = s & 1;                 // == t&1 (ss*8 even)
            // B-frags: lane group lk reads h bytes [ks*64 + lk*16 .. +15]
            const iv4* hb = (const iv4*)hq[t01];
            iv4 B0 = hb[lk], B1 = hb[4 + lk], B2 = hb[8 + lk], B3 = hb[12 + lk];

            iv4 D[8];
            #pragma unroll
            for (int q = 0; q < 8; ++q){
                iv4 z4 = {0, 0, 0, 0};
                D[q] = __builtin_amdgcn_mfma_i32_16x16x64_i8(A[q][0], B0, z4,   0, 0, 0);
                D[q] = __builtin_amdgcn_mfma_i32_16x16x64_i8(A[q][1], B1, D[q], 0, 0, 0);
                D[q] = __builtin_amdgcn_mfma_i32_16x16x64_i8(A[q][2], B2, D[q], 0, 0, 0);
                D[q] = __builtin_amdgcn_mfma_i32_16x16x64_i8(A[q][3], B3, D[q], 0, 0, 0);
            }

            const float* zrow = &zxl[cur][s * 1024 + e];
            float zc0 = zrow[0], zc1 = zrow[256], zc2 = zrow[512], zc3 = zrow[768];

            // de-replicate: pick my (h_, r_) result from each gate's tile pair
            int d0, d1, d2, d3;
#define GSEL(dst, g) { \
            int v0 = selh ? D[2*(g)+1][0] : D[2*(g)][0]; \
            int v1 = selh ? D[2*(g)+1][1] : D[2*(g)][1]; \
            int v2 = selh ? D[2*(g)+1][2] : D[2*(g)][2]; \
            int v3 = selh ? D[2*(g)+1][3] : D[2*(g)][3]; \
            int va = selr1 ? v1 : v0; \
            int vb = selr1 ? v3 : v2; \
            dst = selr2 ? vb : va; }
            GSEL(d0, 0) GSEL(d1, 1) GSEL(d2, 2) GSEL(d3, 3)
#undef GSEL

            float zi = fmaf((float)d0, fs0, zc0);
            float zf = fmaf((float)d1, fs1, zc1);
            float zg = fmaf((float)d2, fs2, zc2);
            float zo = fmaf((float)d3, fs3, zc3);

            float pp = fast_sig(zi) * fast_tanh(zg);
            c_state  = fast_sig(zf) * c_state + pp;
            float hv = fast_sig(zo) * fast_tanh(c_state);

            if (p < 8){
                hsb[s * 256 + e] = hv;
                int qv = (int)rintf(hv * 127.0f);
                ((signed char*)hq[t01 ^ 1])[e] = (signed char)qv;
            }
            BAR();
        }

        // write-late: staged superstep ss+1 regs -> zxl[nxt]
        {
            float4* zln = (float4*)zxl[cur ^ 1];
            zln[tid] = ga; zln[512 + tid] = gb; zln[1024 + tid] = gc; zln[1536 + tid] = gd;
        }
        // issue-early: load superstep ss+2 (guarded; uniform branch)
        if (ss < 1022){
            const float4* zn = zp4 + (size_t)(ss + 2) * 2048;
            ga = zn[tid]; gb = zn[512 + tid]; gc = zn[1024 + tid]; gd = zn[1536 + tid];
        }
    }
    // final flush (superstep 1023's h)
    {
        float4 hv4 = ((const float4*)hsb)[tid];
        ((float4*)(hs + (size_t)1023 * 2048))[tid] = hv4;
    }
}

// ---------------- kernel 4: logits + log_softmax
__global__ __launch_bounds__(128) void k_out(const float* __restrict__ hs,
                                             const float* __restrict__ out_w,
                                             const float* __restrict__ out_b,
                                             float* __restrict__ out){
    __shared__ float hl[256];
    __shared__ float red0[2];
    __shared__ float red1[2];
    int s = blockIdx.x, tid = threadIdx.x;
    hl[tid]       = hs[(size_t)s * 256 + tid];
    hl[tid + 128] = hs[(size_t)s * 256 + 128 + tid];
    __syncthreads();
    const float4* wr = (const float4*)(out_w + (size_t)tid * 256);
    float acc = out_b[tid];
    #pragma unroll 8
    for (int k = 0; k < 64; ++k){
        float4 v = wr[k];
        acc += v.x * hl[4*k] + v.y * hl[4*k+1] + v.z * hl[4*k+2] + v.w * hl[4*k+3];
    }
    float m = acc;
    #pragma unroll
    for (int off = 32; off; off >>= 1) m = fmaxf(m, __shfl_xor(m, off));
    if ((tid & 63) == 0) red0[tid >> 6] = m;
    __syncthreads();
    float M = fmaxf(red0[0], red0[1]);
    float e = __expf(acc - M);
    float ssum = e;
    #pragma unroll
    for (int off = 32; off; off >>= 1) ssum += __shfl_xor(ssum, off);
    if ((tid & 63) == 0) red1[tid >> 6] = ssum;
    __syncthreads();
    float Z = red1[0] + red1[1];
    out[(size_t)s * 128 + tid] = acc - M - __logf(Z);
}

extern "C" void kernel_launch(void* const* d_in, const int* in_sizes, int n_in,
                              void* d_out, int out_size, void* d_ws, size_t ws_size,
                              hipStream_t stream){
    const int*   word_ixs  = (const int*)  d_in[0];
    const int*   char_ixs  = (const int*)  d_in[1];
    const int*   char_lens = (const int*)  d_in[2];
    const float* word_emb  = (const float*)d_in[3];
    const float* char_emb  = (const float*)d_in[4];
    const float* c_wih     = (const float*)d_in[5];
    const float* c_whh     = (const float*)d_in[6];
    const float* c_bih     = (const float*)d_in[7];
    const float* c_bhh     = (const float*)d_in[8];
    const float* w_wih     = (const float*)d_in[9];
    const float* w_whh     = (const float*)d_in[10];
    const float* w_bih     = (const float*)d_in[11];
    const float* w_bhh     = (const float*)d_in[12];
    const float* out_w     = (const float*)d_in[13];
    const float* out_b     = (const float*)d_in[14];
    float* out = (float*)d_out;

    char* ws = (char*)d_ws;
    const size_t OFF_WX  = 0;                        // 8192*192*4  = 6291456
    const size_t OFF_ZX  = OFF_WX + 6291456;         // 8192*1024*4 = 33554432
    const size_t OFF_HS  = OFF_ZX + 33554432;        // 8192*256*4  = 8388608
    const size_t OFF_WQ  = OFF_HS + 8388608;         // 1024*256    = 262144
    const size_t OFF_FS  = OFF_WQ + 262144;          // 1024*4      = 4096
    float* wx    = (float*)(ws + OFF_WX);
    float* zx    = (float*)(ws + OFF_ZX);
    float* hs    = (float*)(ws + OFF_HS);
    int*   wpack = (int*)  (ws + OFF_WQ);
    float* fsc   = (float*)(ws + OFF_FS);

    k_pack <<<dim3(1024), dim3(64),  0, stream>>>(w_whh, wpack, fsc);
    k_char <<<dim3(2048), dim3(256), 0, stream>>>(word_ixs, char_ixs, char_lens,
                                                  word_emb, char_emb,
                                                  c_wih, c_whh, c_bih, c_bhh, wx);
    k_proj <<<dim3(1024), dim3(128), 0, stream>>>(wx, w_wih, w_bih, w_bhh, zx);
    k_scan <<<dim3(1),    dim3(512), 0, stream>>>(zx, wpack, fsc, hs);
    k_out  <<<dim3(8192), dim3(128), 0, stream>>>(hs, out_w, out_b, out);
}